// Round 12
// baseline (6698.392 us; speedup 1.0000x reference)
//
#include <hip/hip_runtime.h>
#include <math.h>

#define N_PTS 16384
#define M_CTR 4096
#define NS 16
#define CIN 64
#define COUT 128
#define CFEAT 67
#define CPB 4          // centers per block in passA
#define NCELL 4096     // 16x16x16 grid (sorting granularity only)
#define PPT 16         // points per thread in FPS

// sorted-pair merge: (a1>=a2) U (b1>=b2) -> exact top-2 in (a1,a2)
__device__ __forceinline__ void pmerge(unsigned long long& a1, unsigned long long& a2,
                                       unsigned long long b1, unsigned long long b2) {
    unsigned long long n1 = a1 > b1 ? a1 : b1;
    unsigned long long lo = a1 > b1 ? b1 : a1;
    unsigned long long m2 = a2 > b2 ? a2 : b2;
    a2 = lo > m2 ? lo : m2;
    a1 = n1;
}

// top-2 u64 merge toward lane 63 via DPP (old=0 = identity for max)
#define DPP_TOP2(CTRL) do { \
    unsigned _o1lo = (unsigned)__builtin_amdgcn_update_dpp(0, (int)(unsigned)k1, CTRL, 0xF, 0xF, false); \
    unsigned _o1hi = (unsigned)__builtin_amdgcn_update_dpp(0, (int)(unsigned)(k1>>32), CTRL, 0xF, 0xF, false); \
    unsigned _o2lo = (unsigned)__builtin_amdgcn_update_dpp(0, (int)(unsigned)k2, CTRL, 0xF, 0xF, false); \
    unsigned _o2hi = (unsigned)__builtin_amdgcn_update_dpp(0, (int)(unsigned)(k2>>32), CTRL, 0xF, 0xF, false); \
    unsigned long long _b1 = ((unsigned long long)_o1hi << 32) | (unsigned long long)_o1lo; \
    unsigned long long _b2 = ((unsigned long long)_o2hi << 32) | (unsigned long long)_o2lo; \
    pmerge(k1, k2, _b1, _b2); \
} while (0)

#define DPP_SWEEP(M) M(0x111); M(0x112); M(0x114); M(0x118); M(0x142); M(0x143)

#define REPEAT16(M) M(0) M(1) M(2) M(3) M(4) M(5) M(6) M(7) \
                    M(8) M(9) M(10) M(11) M(12) M(13) M(14) M(15)

// ---------------- init: counters ----------------
__global__ void init_kernel(int* __restrict__ cnt, int* __restrict__ fill)
{
    int i = blockIdx.x * blockDim.x + threadIdx.x;
    if (i < NCELL) { cnt[i] = 0; fill[i] = 0; }
}

// ---------------- cloud bbox (single block, deterministic) ----------------
__global__ __launch_bounds__(256) void bbox_kernel(const float* __restrict__ p,
                                                   float* __restrict__ gbb)
{
    int t = threadIdx.x, lane = t & 63, w = t >> 6;
    float mnx = 1e30f, mny = 1e30f, mnz = 1e30f;
    float mxx = -1e30f, mxy = -1e30f, mxz = -1e30f;
    for (int i = t; i < N_PTS; i += 256) {
        float x = p[i*3], y = p[i*3+1], z = p[i*3+2];
        mnx = fminf(mnx, x); mny = fminf(mny, y); mnz = fminf(mnz, z);
        mxx = fmaxf(mxx, x); mxy = fmaxf(mxy, y); mxz = fmaxf(mxz, z);
    }
    for (int m = 1; m < 64; m <<= 1) {
        mnx = fminf(mnx, __shfl_xor(mnx, m)); mny = fminf(mny, __shfl_xor(mny, m));
        mnz = fminf(mnz, __shfl_xor(mnz, m));
        mxx = fmaxf(mxx, __shfl_xor(mxx, m)); mxy = fmaxf(mxy, __shfl_xor(mxy, m));
        mxz = fmaxf(mxz, __shfl_xor(mxz, m));
    }
    __shared__ float s[4][6];
    if (lane == 0) { s[w][0]=mnx; s[w][1]=mny; s[w][2]=mnz; s[w][3]=mxx; s[w][4]=mxy; s[w][5]=mxz; }
    __syncthreads();
    if (t == 0) {
        gbb[0] = fminf(fminf(s[0][0], s[1][0]), fminf(s[2][0], s[3][0]));
        gbb[1] = fminf(fminf(s[0][1], s[1][1]), fminf(s[2][1], s[3][1]));
        gbb[2] = fminf(fminf(s[0][2], s[1][2]), fminf(s[2][2], s[3][2]));
        gbb[3] = fmaxf(fmaxf(s[0][3], s[1][3]), fmaxf(s[2][3], s[3][3]));
        gbb[4] = fmaxf(fmaxf(s[0][4], s[1][4]), fmaxf(s[2][4], s[3][4]));
        gbb[5] = fmaxf(fmaxf(s[0][5], s[1][5]), fmaxf(s[2][5], s[3][5]));
    }
}

// ---------------- assign points to 16^3 cells ----------------
__global__ void assign_kernel(const float* __restrict__ p, const float* __restrict__ gbb,
                              int* __restrict__ c_of, int* __restrict__ cnt)
{
    int i = blockIdx.x * blockDim.x + threadIdx.x;
    if (i >= N_PTS) return;
    float bx = gbb[0], by = gbb[1], bz = gbb[2];
    float sx = 15.9999f / fmaxf(gbb[3] - bx, 1e-20f);
    float sy = 15.9999f / fmaxf(gbb[4] - by, 1e-20f);
    float sz = 15.9999f / fmaxf(gbb[5] - bz, 1e-20f);
    float x = p[i*3], y = p[i*3+1], z = p[i*3+2];
    int ix = min(15, max(0, (int)((x - bx) * sx)));
    int iy = min(15, max(0, (int)((y - by) * sy)));
    int iz = min(15, max(0, (int)((z - bz) * sz)));
    int c = (ix << 8) | (iy << 4) | iz;
    c_of[i] = c;
    atomicAdd(&cnt[c], 1);
}

// ---------------- exclusive prefix over 4096 counts ----------------
__global__ __launch_bounds__(1024) void prefix_kernel(const int* __restrict__ cnt,
                                                      int* __restrict__ start)
{
    __shared__ int a[1024];
    int t = threadIdx.x;
    int c0 = cnt[4*t], c1 = cnt[4*t+1], c2 = cnt[4*t+2], c3 = cnt[4*t+3];
    int s = c0 + c1 + c2 + c3;
    a[t] = s; __syncthreads();
    for (int off = 1; off < 1024; off <<= 1) {
        int u = (t >= off) ? a[t - off] : 0;
        __syncthreads();
        a[t] += u;
        __syncthreads();
    }
    int ex = a[t] - s;
    start[4*t]   = ex;
    start[4*t+1] = ex + c0;
    start[4*t+2] = ex + c0 + c1;
    start[4*t+3] = ex + c0 + c1 + c2;
}

// ---------------- scatter into cell-sorted order ----------------
__global__ void scatter_kernel(const float* __restrict__ p, const int* __restrict__ c_of,
                               const int* __restrict__ start, int* __restrict__ fill,
                               float4* __restrict__ sp)
{
    int i = blockIdx.x * blockDim.x + threadIdx.x;
    if (i >= N_PTS) return;
    int c = c_of[i];
    int pos = start[c] + atomicAdd(&fill[c], 1);
    sp[pos] = make_float4(p[i*3], p[i*3+1], p[i*3+2], __int_as_float(i));
}

// ---------------- FPS: thread-local bbox prune + cached top-2 + exact 2-batch ----------------
__global__ __launch_bounds__(1024) void fps_kernel(const float* __restrict__ p,
                                                   const float4* __restrict__ sp,
                                                   int* __restrict__ sel)
{
    __shared__ unsigned long long skw1[16], skw2[16];
    __shared__ float bq[6];
    __shared__ int bnsel;

    const int t = threadIdx.x;
    const int lane = t & 63, wave = t >> 6;
    const int base = t << 4;

    // per-point dist in named registers (SROA-proof)
#define DECL(k) float ds##k = 1e10f;
    REPEAT16(DECL)
#undef DECL

    // tight bbox over this thread's 16 contiguous (cell-sorted) points
    float bmnx = 1e30f, bmny = 1e30f, bmnz = 1e30f;
    float bmxx = -1e30f, bmxy = -1e30f, bmxz = -1e30f;
#define BBX(k) { float4 P = sp[base + k]; \
    bmnx = fminf(bmnx, P.x); bmny = fminf(bmny, P.y); bmnz = fminf(bmnz, P.z); \
    bmxx = fmaxf(bmxx, P.x); bmxy = fmaxf(bmxy, P.y); bmxz = fmaxf(bmxz, P.z); }
    REPEAT16(BBX)
#undef BBX

    float tmax = 1e10f;                              // exact max of own dists
    unsigned long long kc1 = 0ull, kc2 = 0ull;       // cached exact own top-2

    if (t == 0) sel[0] = 0;
    float q1x = p[0], q1y = p[1], q1z = p[2];
    float q2x = 0.f, q2y = 0.f, q2z = 0.f;
    bool two = false, first = true;
    __syncthreads();

    int it = 1;
    while (it < M_CTR) {
        // ---- prune vs own bbox (registers only; skip is provably exact)
        bool act;
        if (first) act = true;
        else {
            float cm = tmax * 1.00001f;
            float ddx = fmaxf(fmaxf(__fsub_rn(bmnx, q1x), __fsub_rn(q1x, bmxx)), 0.f);
            float ddy = fmaxf(fmaxf(__fsub_rn(bmny, q1y), __fsub_rn(q1y, bmxy)), 0.f);
            float ddz = fmaxf(fmaxf(__fsub_rn(bmnz, q1z), __fsub_rn(q1z, bmxz)), 0.f);
            float dm1 = __fadd_rn(__fadd_rn(__fmul_rn(ddx,ddx), __fmul_rn(ddy,ddy)),
                                  __fmul_rn(ddz,ddz));
            act = dm1 < cm;
            if (!act && two) {
                float ex = fmaxf(fmaxf(__fsub_rn(bmnx, q2x), __fsub_rn(q2x, bmxx)), 0.f);
                float ey = fmaxf(fmaxf(__fsub_rn(bmny, q2y), __fsub_rn(q2y, bmxy)), 0.f);
                float ez = fmaxf(fmaxf(__fsub_rn(bmnz, q2z), __fsub_rn(q2z, bmxz)), 0.f);
                float dm2 = __fadd_rn(__fadd_rn(__fmul_rn(ex,ex), __fmul_rn(ey,ey)),
                                      __fmul_rn(ez,ez));
                act = dm2 < cm;
            }
        }

        if (act) {
            // rescan own 16 points: update dists, rebuild tmax + exact top-2
            float nmax = -1.0f;
            unsigned long long k1 = 0ull, k2 = 0ull;
#define UPD(k) { \
            float4 P = sp[base + k]; \
            float dx = __fsub_rn(P.x, q1x), dy = __fsub_rn(P.y, q1y), dz = __fsub_rn(P.z, q1z); \
            float d2 = __fadd_rn(__fadd_rn(__fmul_rn(dx,dx), __fmul_rn(dy,dy)), \
                                 __fmul_rn(dz,dz)); \
            float nd = fminf(ds##k, d2); \
            if (two) { \
                float ex = __fsub_rn(P.x, q2x), ey = __fsub_rn(P.y, q2y), ez = __fsub_rn(P.z, q2z); \
                float e2 = __fadd_rn(__fadd_rn(__fmul_rn(ex,ex), __fmul_rn(ey,ey)), \
                                     __fmul_rn(ez,ez)); \
                nd = fminf(nd, e2); \
            } \
            ds##k = nd; \
            nmax = fmaxf(nmax, nd); \
            unsigned long long kk = ((unsigned long long)__float_as_uint(nd) << 32) \
                                  | (unsigned long long)(~(unsigned)__float_as_int(P.w)); \
            if (kk > k1) { k2 = k1; k1 = kk; } else if (kk > k2) { k2 = kk; } }
            REPEAT16(UPD)
#undef UPD
            tmax = nmax;
            kc1 = k1; kc2 = k2;
        }

        // ---- wave top-2 over (cached or fresh) pairs
        unsigned long long k1 = kc1, k2 = kc2;
        DPP_SWEEP(DPP_TOP2);
        if (lane == 63) { skw1[wave] = k1; skw2[wave] = k2; }
        __syncthreads();

        // ---- wave 0: global top-2, accept test, q fetch, broadcast
        if (wave == 0) {
            k1 = (lane < 16) ? skw1[lane] : 0ull;
            k2 = (lane < 16) ? skw2[lane] : 0ull;
            DPP_SWEEP(DPP_TOP2);
            if (lane == 63) {
                unsigned long long A1 = k1, A2 = k2;
                int s1 = (int)(~(unsigned)(A1 & 0xFFFFFFFFull));
                int s2 = (int)(~(unsigned)(A2 & 0xFFFFFFFFull));
                sel[it] = s1;
                float nq1x = p[s1*3+0], nq1y = p[s1*3+1], nq1z = p[s1*3+2];
                float bx2 = p[s2*3+0], by2 = p[s2*3+1], bz2 = p[s2*3+2];
                int nsel = 1;
                if (A2 != 0ull && it + 1 < M_CTR) {
                    // exact: if s1's update leaves the global #2 key unchanged,
                    // every other key can only drop below it -> s2 is next pick.
                    float dx = __fsub_rn(bx2, nq1x), dy = __fsub_rn(by2, nq1y), dz = __fsub_rn(bz2, nq1z);
                    float d2b = __fadd_rn(__fadd_rn(__fmul_rn(dx,dx), __fmul_rn(dy,dy)),
                                          __fmul_rn(dz,dz));
                    float db = __uint_as_float((unsigned)(A2 >> 32));
                    if (d2b >= db) { nsel = 2; sel[it + 1] = s2; }
                }
                bq[0] = nq1x; bq[1] = nq1y; bq[2] = nq1z;
                bq[3] = bx2;  bq[4] = by2;  bq[5] = bz2;
                bnsel = nsel;
            }
        }
        __syncthreads();
        int nsel = bnsel;
        q1x = bq[0]; q1y = bq[1]; q1z = bq[2];
        two = (nsel == 2);
        if (two) { q2x = bq[3]; q2y = bq[4]; q2z = bq[5]; }
        first = false;
        it += nsel;
    }
}

// ---------------- prep: pp2, gather n_p/n_n, write n_o ----------------
__global__ void prep_kernel(const float* __restrict__ p, const float* __restrict__ nrm,
                            const int* __restrict__ sel, float* __restrict__ pp2,
                            float* __restrict__ out)
{
    int i = blockIdx.x * blockDim.x + threadIdx.x;
    if (i < N_PTS) {
        float x = p[i*3], y = p[i*3+1], z = p[i*3+2];
        pp2[i] = __fadd_rn(__fadd_rn(__fmul_rn(x,x), __fmul_rn(y,y)), __fmul_rn(z,z));
    }
    if (i < M_CTR) {
        int j = sel[i];
        out[i*3+0] = p[j*3+0]; out[i*3+1] = p[j*3+1]; out[i*3+2] = p[j*3+2];
        out[12288 + i*3+0] = nrm[j*3+0];
        out[12288 + i*3+1] = nrm[j*3+1];
        out[12288 + i*3+2] = nrm[j*3+2];
    }
    if (i == 0) out[548864] = (float)M_CTR;   // n_o
}

// ---------------- kNN: one wave per center, per-lane sorted top-16 ----------------
__global__ __launch_bounds__(256) void knn_kernel(const float* __restrict__ p,
                                                  const float* __restrict__ pp2,
                                                  const float* __restrict__ np /* n_p */,
                                                  int* __restrict__ knn)
{
    const int lane = threadIdx.x & 63;
    const int wave = threadIdx.x >> 6;
    const int c = blockIdx.x * 4 + wave;

    float cx = np[c*3], cy = np[c*3+1], cz = np[c*3+2];
    float c2 = __fadd_rn(__fadd_rn(__fmul_rn(cx,cx), __fmul_rn(cy,cy)), __fmul_rn(cz,cz));

    float hd[16]; int hi[16];
#pragma unroll
    for (int k = 0; k < 16; ++k) { hd[k] = 1e30f; hi[k] = 0x7fffffff; }

    for (int t = 0; t < N_PTS/64; ++t) {
        int j = t*64 + lane;
        float px = p[j*3+0], py = p[j*3+1], pz = p[j*3+2];
        float dot = __fadd_rn(__fadd_rn(__fmul_rn(cx,px), __fmul_rn(cy,py)),
                              __fmul_rn(cz,pz));
        float d2  = __fsub_rn(__fadd_rn(c2, pp2[j]), __fmul_rn(2.0f, dot));
        if (d2 < hd[15]) {
#pragma unroll
            for (int k = 15; k >= 1; --k) {
                bool up   = d2 < hd[k-1];
                bool here = d2 < hd[k];
                hd[k] = up ? hd[k-1] : (here ? d2 : hd[k]);
                hi[k] = up ? hi[k-1] : (here ? j  : hi[k]);
            }
            if (d2 < hd[0]) { hd[0] = d2; hi[0] = j; }
        }
    }

    for (int r = 0; r < 16; ++r) {
        float wv = hd[0]; int wi = hi[0];
#pragma unroll
        for (int m = 1; m < 64; m <<= 1) {
            float ov = __shfl_xor(wv, m);
            int   oi = __shfl_xor(wi, m);
            bool b = (ov < wv) || (ov == wv && oi < wi);
            wv = b ? ov : wv; wi = b ? oi : wi;
        }
        if (hi[0] == wi) {
            knn[c*16 + r] = wi;
#pragma unroll
            for (int k = 0; k < 15; ++k) { hd[k] = hd[k+1]; hi[k] = hi[k+1]; }
            hd[15] = 1e30f; hi[15] = 0x7fffffff;
        }
    }
}

// ---------------- pass A: feat build + GEMM + stats + ymax/ymin ----------------
__global__ __launch_bounds__(128) void passA_kernel(const float* __restrict__ p,
                                                    const float* __restrict__ xf,
                                                    const float* __restrict__ W,
                                                    const int* __restrict__ knn,
                                                    const float* __restrict__ out /* n_p */,
                                                    float* __restrict__ ymax,
                                                    float* __restrict__ ymin,
                                                    float* __restrict__ partials)
{
    __shared__ float Wt[CFEAT][COUT];
    __shared__ float ft[CPB][NS][CFEAT];
    __shared__ float bsum[CPB][COUT], bssq[CPB][COUT];

    const int t = threadIdx.x;
    const int mbase = blockIdx.x * CPB;

    for (int c = 0; c < CFEAT; ++c) Wt[c][t] = W[t*CFEAT + c];

    {
        int r = t >> 1, half = t & 1;
        int ci = r >> 4, s = r & 15;
        int m = mbase + ci;
        int nb = knn[m*NS + s];
        if (half == 0) {
            ft[ci][s][0] = __fsub_rn(p[nb*3+0], out[m*3+0]);
            ft[ci][s][1] = __fsub_rn(p[nb*3+1], out[m*3+1]);
            ft[ci][s][2] = __fsub_rn(p[nb*3+2], out[m*3+2]);
        }
        for (int c = half*32; c < half*32 + 32; ++c)
            ft[ci][s][3+c] = xf[nb*CIN + c];
    }
    __syncthreads();

    const int ci = t >> 5, l = t & 31;
    float acc[NS][4];
#pragma unroll
    for (int s = 0; s < NS; ++s) { acc[s][0]=0.f; acc[s][1]=0.f; acc[s][2]=0.f; acc[s][3]=0.f; }

    for (int c = 0; c < CFEAT; ++c) {
        float w0 = Wt[c][l], w1 = Wt[c][l+32], w2 = Wt[c][l+64], w3 = Wt[c][l+96];
#pragma unroll
        for (int s = 0; s < NS; ++s) {
            float f = ft[ci][s][c];
            acc[s][0] = fmaf(f, w0, acc[s][0]);
            acc[s][1] = fmaf(f, w1, acc[s][1]);
            acc[s][2] = fmaf(f, w2, acc[s][2]);
            acc[s][3] = fmaf(f, w3, acc[s][3]);
        }
    }

    const int m = mbase + ci;
#pragma unroll
    for (int j = 0; j < 4; ++j) {
        int o = l + 32*j;
        float s = 0.f, q = 0.f, mx = -1e30f, mn = 1e30f;
#pragma unroll
        for (int sidx = 0; sidx < NS; ++sidx) {
            float v = acc[sidx][j];
            s += v; q = fmaf(v, v, q);
            mx = fmaxf(mx, v); mn = fminf(mn, v);
        }
        bsum[ci][o] = s;
        bssq[ci][o] = q;
        ymax[m*COUT + o] = mx;
        ymin[m*COUT + o] = mn;
    }
    __syncthreads();
    if (t < COUT) {
        float s = bsum[0][t] + bsum[1][t] + bsum[2][t] + bsum[3][t];
        float q = bssq[0][t] + bssq[1][t] + bssq[2][t] + bssq[3][t];
        partials[t*1024          + blockIdx.x] = s;
        partials[(COUT + t)*1024 + blockIdx.x] = q;
    }
}

// ---------------- BN stats reduce -> scale/shift ----------------
__global__ __launch_bounds__(256) void bnstat_kernel(const float* __restrict__ partials,
                                                     const float* __restrict__ gamma,
                                                     const float* __restrict__ beta,
                                                     float* __restrict__ scaleshift)
{
    __shared__ float red[256];
    int t = threadIdx.x;
    const float4* v4 = (const float4*)(partials + t*1024);
    float s = 0.f;
    for (int i = 0; i < 256; ++i) {
        float4 v = v4[i];
        s += v.x; s += v.y; s += v.z; s += v.w;
    }
    red[t] = s;
    __syncthreads();
    if (t < COUT) {
        const float inv = 1.0f / 65536.0f;
        float mean = red[t] * inv;
        float var  = red[COUT + t] * inv - mean*mean;
        float rstd = rsqrtf(var + 1e-5f);
        float g = gamma[t] * rstd;
        scaleshift[t]        = g;
        scaleshift[COUT + t] = beta[t] - mean * g;
    }
}

// ---------------- final: BN apply + ReLU on the pooled extreme ----------------
__global__ void final_kernel(float* __restrict__ y,
                             const float* __restrict__ ymin,
                             const float* __restrict__ scaleshift)
{
    int i = blockIdx.x * blockDim.x + threadIdx.x;
    if (i >= M_CTR * COUT) return;
    int o = i & (COUT - 1);
    float a = scaleshift[o], b = scaleshift[COUT + o];
    float v = (a >= 0.f) ? y[i] : ymin[i];
    float z = fmaf(a, v, b);
    y[i] = fmaxf(z, 0.f);
}

extern "C" void kernel_launch(void* const* d_in, const int* in_sizes, int n_in,
                              void* d_out, int out_size, void* d_ws, size_t ws_size,
                              hipStream_t stream)
{
    const float* p     = (const float*)d_in[0];
    const float* nrm   = (const float*)d_in[1];
    const float* xf    = (const float*)d_in[2];
    // d_in[3] = o (unused: single batch, static sizes)
    const float* W     = (const float*)d_in[4];
    const float* gamma = (const float*)d_in[5];
    const float* beta  = (const float*)d_in[6];

    float* out = (float*)d_out;
    char* ws = (char*)d_ws;
    int*   sel        = (int*)(ws + 0);            // 16 KB
    float* pp2        = (float*)(ws + 16384);      // 64 KB
    int*   knn        = (int*)(ws + 81920);        // 256 KB (overlaid by sp during FPS)
    float* ymin       = (float*)(ws + 344064);     // 2 MB  (head overlaid by FPS scratch)
    float* partials   = (float*)(ws + 2441216);    // 1 MB
    float* scaleshift = (float*)(ws + 3489792);    // 1 KB

    // FPS scratch overlays (consumed before their hosts are written):
    float4*   sp        = (float4*)(ws + 81920);            // 256 KB in knn region
    char*     yb        = ws + 344064;                      // ymin region
    int*      c_of      = (int*)(yb + 65536);               // 64 KB
    int*      cellcnt   = (int*)(yb + 131072);              // 16 KB
    int*      cellfill  = (int*)(yb + 147456);              // 16 KB
    int*      cellstart = (int*)(yb + 163840);              // 16 KB
    float*    gbb       = (float*)(yb + 180224);            // 24 B

    float* ymax = out + 24576;  // y region of d_out

    init_kernel   <<<16, 256, 0, stream>>>(cellcnt, cellfill);
    bbox_kernel   <<<1,  256, 0, stream>>>(p, gbb);
    assign_kernel <<<64, 256, 0, stream>>>(p, gbb, c_of, cellcnt);
    prefix_kernel <<<1,  1024, 0, stream>>>(cellcnt, cellstart);
    scatter_kernel<<<64, 256, 0, stream>>>(p, c_of, cellstart, cellfill, sp);
    fps_kernel    <<<1,  1024, 0, stream>>>(p, sp, sel);
    prep_kernel   <<<64, 256, 0, stream>>>(p, nrm, sel, pp2, out);
    knn_kernel    <<<1024, 256, 0, stream>>>(p, pp2, out, knn);
    passA_kernel  <<<M_CTR/CPB, 128, 0, stream>>>(p, xf, W, knn, out, ymax, ymin, partials);
    bnstat_kernel <<<1, 256, 0, stream>>>(partials, gamma, beta, scaleshift);
    final_kernel  <<<2048, 256, 0, stream>>>(ymax, ymin, scaleshift);
}